// Round 2
// baseline (1235.595 us; speedup 1.0000x reference)
//
#include <hip/hip_runtime.h>
#include <hip/hip_bf16.h>

#define B_    32
#define C_    128
#define H_    56
#define W_    56
#define N_    3136
#define HK_   15
#define NK_   225
#define D_    64

__device__ __forceinline__ float b2f(unsigned short u) {
    union { float f; unsigned int i; } x;
    x.i = ((unsigned int)u) << 16;
    return x.f;
}

__device__ __forceinline__ unsigned short f2b(float f) {
    __hip_bfloat16 h = __float2bfloat16(f);
    return *(unsigned short*)&h;
}

// ---------------- Kernel 1: depthwise 4x4 s4 conv + BN + ReLU + scale + BN ----------------
__global__ void sr_kernel(const float* __restrict__ x,
                          const float* __restrict__ sr1_w,
                          const float* __restrict__ sr1_g,
                          const float* __restrict__ sr1_b,
                          const float* __restrict__ sr1_m,
                          const float* __restrict__ sr1_v,
                          const float* __restrict__ sr2_w,
                          const float* __restrict__ sr2_g,
                          const float* __restrict__ sr2_b,
                          const float* __restrict__ sr2_m,
                          const float* __restrict__ sr2_v,
                          float* __restrict__ kv1) {
    int bc = blockIdx.x;            // b*128 + c
    int c  = bc & (C_ - 1);
    int p  = threadIdx.x;
    if (p >= NK_) return;
    int oy = p / HK_, ox = p % HK_;
    const float* xp = x + (size_t)bc * (H_ * W_);
    float s = 0.f;
#pragma unroll
    for (int ky = 0; ky < 4; ++ky) {
        int iy = oy * 4 - 2 + ky;
        if (iy < 0 || iy >= H_) continue;
#pragma unroll
        for (int kx = 0; kx < 4; ++kx) {
            int ix = ox * 4 - 2 + kx;
            if (ix < 0 || ix >= W_) continue;
            s += xp[iy * W_ + ix] * sr1_w[c * 16 + ky * 4 + kx];
        }
    }
    float inv1 = sr1_g[c] * rsqrtf(sr1_v[c] + 1e-5f);
    s = (s - sr1_m[c]) * inv1 + sr1_b[c];
    s = fmaxf(s, 0.f);
    s *= sr2_w[c];
    float inv2 = sr2_g[c] * rsqrtf(sr2_v[c] + 1e-5f);
    s = (s - sr2_m[c]) * inv2 + sr2_b[c];
    kv1[(size_t)bc * NK_ + p] = s;
}

// ---------------- Kernel 2: depthwise 3x3 local conv + bias + residual ----------------
__global__ void local_kernel(const float* __restrict__ kv1,
                             const float* __restrict__ local_w,
                             const float* __restrict__ local_b,
                             float* __restrict__ kv2) {
    int bc = blockIdx.x;
    int c  = bc & (C_ - 1);
    int p  = threadIdx.x;
    if (p >= NK_) return;
    int oy = p / HK_, ox = p % HK_;
    const float* kp = kv1 + (size_t)bc * NK_;
    float v = kp[p] + local_b[c];
#pragma unroll
    for (int dy = -1; dy <= 1; ++dy) {
        int yy = oy + dy;
        if (yy < 0 || yy >= HK_) continue;
#pragma unroll
        for (int dx = -1; dx <= 1; ++dx) {
            int xx = ox + dx;
            if (xx < 0 || xx >= HK_) continue;
            v += kp[yy * HK_ + xx] * local_w[c * 9 + (dy + 1) * 3 + (dx + 1)];
        }
    }
    kv2[(size_t)bc * NK_ + p] = v;
}

// ---------------- Kernel 3: kv projection (1x1 conv, 256 out channels) ----------------
// k stored pre-scaled by 0.125 as [b][h][e][225] bf16, v as [b][h][225][e] bf16
__global__ void kvproj_kernel(const float* __restrict__ kv2,
                              const float* __restrict__ kv_w,
                              const float* __restrict__ kv_b,
                              unsigned short* __restrict__ kbuf,
                              unsigned short* __restrict__ vbuf) {
    int bo = blockIdx.x;            // b*256 + o
    int b  = bo >> 8;
    int o  = bo & 255;
    int p  = threadIdx.x;
    if (p >= NK_) return;
    const float* kp = kv2 + (size_t)b * C_ * NK_;
    float acc = kv_b[o];
    for (int c = 0; c < C_; ++c) {
        acc += kp[c * NK_ + p] * kv_w[o * C_ + c];
    }
    if (o < 128) {
        int h = o >> 6, e = o & 63;
        kbuf[(((size_t)b * 2 + h) * D_ + e) * NK_ + p] = f2b(acc * 0.125f);
    } else {
        int oe = o - 128;
        int h = oe >> 6, e = oe & 63;
        vbuf[(((size_t)b * 2 + h) * NK_ + p) * D_ + e] = f2b(acc);
    }
}

// ---------------- Kernel 4: fused q-projection + attention ----------------
// one block per (b, h, 64-row tile of N). 256 threads.
__global__ __launch_bounds__(256) void attn_kernel(
        const float* __restrict__ x,
        const float* __restrict__ q_w,
        const float* __restrict__ q_b,
        const unsigned short* __restrict__ kbuf,
        const unsigned short* __restrict__ vbuf,
        float* __restrict__ out) {
    int t   = blockIdx.x;   // 0..48
    int h   = blockIdx.y;   // 0..1
    int b   = blockIdx.z;   // 0..31
    int n0  = t * 64;
    int tid = threadIdx.x;

    __shared__ unsigned short kt[64][228];   // k[e][m], zero-padded to 228
    __shared__ unsigned short vt[225][64];   // v[m][e]
    __shared__ float qs[64][64];             // q[j][e]
    __shared__ float rowinv[64];
    __shared__ union {
        struct { unsigned short xt[128][64]; unsigned short qwT[128][68]; } s1;
        float P[64][229];
    } u;

    // stage q_w (transposed, padded, cast to bf16) and x tile (cast to bf16)
    for (int idx = tid; idx < 64 * 128; idx += 256) {
        int e = idx >> 7, c = idx & 127;
        u.s1.qwT[c][e] = f2b(q_w[((size_t)(h * 64 + e)) * 128 + c]);
    }
    for (int idx = tid; idx < 128 * 64; idx += 256) {
        int c = idx >> 6, j = idx & 63;
        u.s1.xt[c][j] = f2b(x[((size_t)b * 128 + c) * (size_t)N_ + n0 + j]);
    }
    // stage k (already scaled) and v
    const unsigned short* kp = kbuf + ((size_t)b * 2 + h) * 64 * NK_;
    for (int idx = tid; idx < 64 * 228; idx += 256) {
        int e = idx / 228, m = idx % 228;
        kt[e][m] = (m < NK_) ? kp[e * NK_ + m] : (unsigned short)0;
    }
    const unsigned short* vp = vbuf + ((size_t)b * 2 + h) * NK_ * 64;
    for (int idx = tid; idx < NK_ * 64; idx += 256) {
        vt[idx >> 6][idx & 63] = vp[idx];
    }
    __syncthreads();

    // q[j][e] = sum_c x[c][j] * qw[e][c] + q_b[e]
#pragma unroll
    for (int r = 0; r < 4; ++r) {
        int flat = r * 256 + tid;
        int j = flat >> 4, e0 = (flat & 15) * 4;
        float acc[4];
#pragma unroll
        for (int i = 0; i < 4; ++i) acc[i] = q_b[h * 64 + e0 + i];
        for (int c = 0; c < 128; ++c) {
            float xv = b2f(u.s1.xt[c][j]);
            ushort4 w4 = *(const ushort4*)&u.s1.qwT[c][e0];
            acc[0] += xv * b2f(w4.x);
            acc[1] += xv * b2f(w4.y);
            acc[2] += xv * b2f(w4.z);
            acc[3] += xv * b2f(w4.w);
        }
#pragma unroll
        for (int i = 0; i < 4; ++i) qs[j][e0 + i] = acc[i];
    }
    __syncthreads();

    // S[j][m] = sum_e q[j][e] * k[e][m]   (k pre-scaled by 0.125)
    for (int flat = tid; flat < 64 * 57; flat += 256) {
        int j = flat / 57, m0 = (flat % 57) * 4;
        float acc[4] = {0.f, 0.f, 0.f, 0.f};
        for (int e = 0; e < 64; ++e) {
            float qv = qs[j][e];
            ushort4 k4 = *(const ushort4*)&kt[e][m0];
            acc[0] += qv * b2f(k4.x);
            acc[1] += qv * b2f(k4.y);
            acc[2] += qv * b2f(k4.z);
            acc[3] += qv * b2f(k4.w);
        }
#pragma unroll
        for (int i = 0; i < 4; ++i) u.P[j][m0 + i] = acc[i];
    }
    __syncthreads();

    // softmax over m (225 valid)
    if (tid < 64) {
        int j = tid;
        float mx = -1e30f;
        for (int m = 0; m < NK_; ++m) mx = fmaxf(mx, u.P[j][m]);
        float sm = 0.f;
        for (int m = 0; m < NK_; ++m) {
            float pe = __expf(u.P[j][m] - mx);
            u.P[j][m] = pe;
            sm += pe;
        }
        rowinv[j] = 1.f / sm;
    }
    __syncthreads();

    // out[j][e] = (sum_m P[j][m] * v[m][e]) * rowinv[j]
#pragma unroll
    for (int r = 0; r < 4; ++r) {
        int flat = r * 256 + tid;
        int g = flat >> 6, j = flat & 63;
        int e0 = g * 4;
        float acc[4] = {0.f, 0.f, 0.f, 0.f};
        for (int m = 0; m < NK_; ++m) {
            float pv = u.P[j][m];
            ushort4 v4 = *(const ushort4*)&vt[m][e0];
            acc[0] += pv * b2f(v4.x);
            acc[1] += pv * b2f(v4.y);
            acc[2] += pv * b2f(v4.z);
            acc[3] += pv * b2f(v4.w);
        }
        float ri = rowinv[j];
        size_t base = ((size_t)b * 128 + h * 64 + e0) * (size_t)N_ + n0 + j;
        out[base]          = acc[0] * ri;
        out[base + N_]     = acc[1] * ri;
        out[base + 2 * N_] = acc[2] * ri;
        out[base + 3 * N_] = acc[3] * ri;
    }
}

extern "C" void kernel_launch(void* const* d_in, const int* in_sizes, int n_in,
                              void* d_out, int out_size, void* d_ws, size_t ws_size,
                              hipStream_t stream) {
    const float* x       = (const float*)d_in[0];
    const float* q_w     = (const float*)d_in[1];
    const float* q_b     = (const float*)d_in[2];
    const float* kv_w    = (const float*)d_in[3];
    const float* kv_b    = (const float*)d_in[4];
    const float* sr1_w   = (const float*)d_in[5];
    const float* sr1_g   = (const float*)d_in[6];
    const float* sr1_b   = (const float*)d_in[7];
    const float* sr1_m   = (const float*)d_in[8];
    const float* sr1_v   = (const float*)d_in[9];
    const float* sr2_w   = (const float*)d_in[10];
    const float* sr2_g   = (const float*)d_in[11];
    const float* sr2_b   = (const float*)d_in[12];
    const float* sr2_m   = (const float*)d_in[13];
    const float* sr2_v   = (const float*)d_in[14];
    const float* local_w = (const float*)d_in[15];
    const float* local_b = (const float*)d_in[16];

    // workspace layout
    float* kv1 = (float*)d_ws;                       // 32*128*225 f32
    float* kv2 = kv1 + (size_t)B_ * C_ * NK_;        // 32*128*225 f32
    unsigned short* kbuf = (unsigned short*)(kv2 + (size_t)B_ * C_ * NK_); // 32*2*64*225 bf16
    unsigned short* vbuf = kbuf + (size_t)B_ * 2 * D_ * NK_;               // 32*2*225*64 bf16

    sr_kernel<<<B_ * C_, 256, 0, stream>>>(x, sr1_w, sr1_g, sr1_b, sr1_m, sr1_v,
                                           sr2_w, sr2_g, sr2_b, sr2_m, sr2_v, kv1);
    local_kernel<<<B_ * C_, 256, 0, stream>>>(kv1, local_w, local_b, kv2);
    kvproj_kernel<<<B_ * 256, 256, 0, stream>>>(kv2, kv_w, kv_b, kbuf, vbuf);
    attn_kernel<<<dim3(49, 2, B_), 256, 0, stream>>>(x, q_w, q_b, kbuf, vbuf,
                                                     (float*)d_out);
}

// Round 3
// 203.073 us; speedup vs baseline: 6.0845x; 6.0845x over previous
//
#include <hip/hip_runtime.h>
#include <hip/hip_bf16.h>

#define B_    32
#define C_    128
#define H_    56
#define W_    56
#define N_    3136
#define HK_   15
#define NK_   225
#define D_    64

typedef __attribute__((ext_vector_type(8))) short bf16x8;
typedef __attribute__((ext_vector_type(4))) float f32x4;

__device__ __forceinline__ float b2f(unsigned short u) {
    union { float f; unsigned int i; } x;
    x.i = ((unsigned int)u) << 16;
    return x.f;
}
__device__ __forceinline__ unsigned short f2b(float f) {
    __hip_bfloat16 h = __float2bfloat16(f);
    return *(unsigned short*)&h;
}

// ---------------- Kernel 1: depthwise 4x4 s4 conv + BN + ReLU + scale + BN ----------------
__global__ void sr_kernel(const float* __restrict__ x,
                          const float* __restrict__ sr1_w,
                          const float* __restrict__ sr1_g,
                          const float* __restrict__ sr1_b,
                          const float* __restrict__ sr1_m,
                          const float* __restrict__ sr1_v,
                          const float* __restrict__ sr2_w,
                          const float* __restrict__ sr2_g,
                          const float* __restrict__ sr2_b,
                          const float* __restrict__ sr2_m,
                          const float* __restrict__ sr2_v,
                          float* __restrict__ kv1) {
    int bc = blockIdx.x;
    int c  = bc & (C_ - 1);
    int p  = threadIdx.x;
    if (p >= NK_) return;
    int oy = p / HK_, ox = p % HK_;
    const float* xp = x + (size_t)bc * (H_ * W_);
    float s = 0.f;
#pragma unroll
    for (int ky = 0; ky < 4; ++ky) {
        int iy = oy * 4 - 2 + ky;
        if (iy < 0 || iy >= H_) continue;
#pragma unroll
        for (int kx = 0; kx < 4; ++kx) {
            int ix = ox * 4 - 2 + kx;
            if (ix < 0 || ix >= W_) continue;
            s += xp[iy * W_ + ix] * sr1_w[c * 16 + ky * 4 + kx];
        }
    }
    float inv1 = sr1_g[c] * rsqrtf(sr1_v[c] + 1e-5f);
    s = (s - sr1_m[c]) * inv1 + sr1_b[c];
    s = fmaxf(s, 0.f);
    s *= sr2_w[c];
    float inv2 = sr2_g[c] * rsqrtf(sr2_v[c] + 1e-5f);
    s = (s - sr2_m[c]) * inv2 + sr2_b[c];
    kv1[(size_t)bc * NK_ + p] = s;
}

// ---------------- Kernel 2: depthwise 3x3 local conv + bias + residual ----------------
__global__ void local_kernel(const float* __restrict__ kv1,
                             const float* __restrict__ local_w,
                             const float* __restrict__ local_b,
                             float* __restrict__ kv2) {
    int bc = blockIdx.x;
    int c  = bc & (C_ - 1);
    int p  = threadIdx.x;
    if (p >= NK_) return;
    int oy = p / HK_, ox = p % HK_;
    const float* kp = kv1 + (size_t)bc * NK_;
    float v = kp[p] + local_b[c];
#pragma unroll
    for (int dy = -1; dy <= 1; ++dy) {
        int yy = oy + dy;
        if (yy < 0 || yy >= HK_) continue;
#pragma unroll
        for (int dx = -1; dx <= 1; ++dx) {
            int xx = ox + dx;
            if (xx < 0 || xx >= HK_) continue;
            v += kp[yy * HK_ + xx] * local_w[c * 9 + (dy + 1) * 3 + (dx + 1)];
        }
    }
    kv2[(size_t)bc * NK_ + p] = v;
}

// ---------------- Kernel 3: kv projection, LDS-staged ----------------
// kbuf: K^T per head, [b][h][m(225)][e(64)] bf16, pre-scaled by 0.125
// vbuf: V^T per head, [b][h][e(64)][m(256 padded)] bf16, cols 225..255 = 0
__global__ __launch_bounds__(256) void kvproj_kernel(
        const float* __restrict__ kv2,
        const float* __restrict__ kv_w,
        const float* __restrict__ kv_b,
        unsigned short* __restrict__ kbuf,
        unsigned short* __restrict__ vbuf) {
    int b  = blockIdx.x;
    int og = blockIdx.y;        // 8 groups of 32 output channels
    int tid = threadIdx.x;
    __shared__ unsigned short kl[128 * 228];

    for (int c = (tid >> 6); c < 128; c += 4) {
        for (int mm = (tid & 63); mm < 228; mm += 64) {
            float v = (mm < NK_) ? kv2[((size_t)b * 128 + c) * NK_ + mm] : 0.f;
            kl[c * 228 + mm] = f2b(v);
        }
    }
    __syncthreads();

    int p  = tid;
    int pc = p < NK_ ? p : NK_ - 1;   // clamp for compute; stores guarded
    int obase = og * 32;
#pragma unroll
    for (int ot = 0; ot < 4; ++ot) {
        float acc[8];
#pragma unroll
        for (int oo = 0; oo < 8; ++oo) acc[oo] = kv_b[obase + ot * 8 + oo];
        for (int c = 0; c < 128; ++c) {
            float xv = b2f(kl[c * 228 + pc]);
#pragma unroll
            for (int oo = 0; oo < 8; ++oo)
                acc[oo] += xv * kv_w[(obase + ot * 8 + oo) * 128 + c];
        }
#pragma unroll
        for (int oo = 0; oo < 8; ++oo) {
            int o = obase + ot * 8 + oo;
            if (o < 128) {
                if (p < NK_) {
                    int h = o >> 6, e = o & 63;
                    kbuf[(((size_t)b * 2 + h) * NK_ + p) * 64 + e] = f2b(acc[oo] * 0.125f);
                }
            } else {
                int oe = o - 128;
                int h = oe >> 6, e = oe & 63;
                unsigned short val = (p < NK_) ? f2b(acc[oo]) : (unsigned short)0;
                vbuf[(((size_t)b * 2 + h) * 64 + e) * 256 + p] = val;
            }
        }
    }
}

// ---------------- Kernel 4: fused MFMA q-proj + attention ----------------
// byte-offset macros with XOR swizzle (row&7)<<4 spreads banks
#define XTB(j, c) ((j) * 256 + (((c) * 2) ^ (((j) & 7) << 4)))
#define QWB(e, c) ((e) * 256 + (((c) * 2) ^ (((e) & 7) << 4)))
#define KTB(m, e) ((m) * 128 + (((e) * 2) ^ (((m) & 7) << 4)))
#define QSB(j, e) ((j) * 128 + (((e) * 2) ^ (((j) & 7) << 4)))
#define PSB(j, m) ((j) * 512 + (((m) * 2) ^ (((j) & 7) << 4)))

__global__ __launch_bounds__(256, 2) void attn_kernel(
        const float* __restrict__ x,
        const float* __restrict__ q_w,
        const float* __restrict__ q_b,
        const unsigned short* __restrict__ kbuf,
        const unsigned short* __restrict__ vbuf,
        float* __restrict__ out) {
    int jt = blockIdx.x;        // 0..48
    int h  = blockIdx.y;        // 0..1
    int bb = blockIdx.z;        // 0..31
    int n0 = jt * 64;
    int bh = bb * 2 + h;
    int tid = threadIdx.x;
    int lo = tid & 15;          // lane&15
    int hi = (tid >> 4) & 3;    // lane>>4
    int jw = (tid >> 6) * 16;   // wave's 16-row base

    __shared__ union {
        struct { unsigned short xt[64 * 128]; unsigned short qw[64 * 128]; } p1;
        unsigned short ps[64 * 256];
    } RA;
    __shared__ union {
        unsigned short kt[240 * 64];
        float olds[64 * 65];
    } RB;
    __shared__ unsigned short qs[64 * 64];

    char* xtB = (char*)RA.p1.xt;
    char* qwB = (char*)RA.p1.qw;
    char* psB = (char*)RA.ps;
    char* ktB = (char*)RB.kt;
    char* qsB = (char*)qs;

    // ---- P1: stage XT (x^T, reg-transpose), QW (q_w rows), KT (kbuf rows) ----
#pragma unroll
    for (int it = 0; it < 8; ++it) {
        int j  = tid & 63;
        int c0 = (tid >> 6) * 4 + it * 16;
        const float* xp = x + ((size_t)bb * 128 + c0) * N_ + n0 + j;
        ushort4 u;
        u.x = f2b(xp[0]);
        u.y = f2b(xp[(size_t)N_]);
        u.z = f2b(xp[2 * (size_t)N_]);
        u.w = f2b(xp[3 * (size_t)N_]);
        *(ushort4*)(xtB + XTB(j, c0)) = u;
    }
#pragma unroll
    for (int it = 0; it < 8; ++it) {
        int idx = it * 256 + tid;
        int e = idx >> 5, c0 = (idx & 31) * 4;
        const float4 w4 = *(const float4*)&q_w[((size_t)(h * 64 + e)) * 128 + c0];
        ushort4 u;
        u.x = f2b(w4.x); u.y = f2b(w4.y); u.z = f2b(w4.z); u.w = f2b(w4.w);
        *(ushort4*)(qwB + QWB(e, c0)) = u;
    }
#pragma unroll
    for (int it = 0; it < 15; ++it) {
        int idx = it * 256 + tid;
        int m = idx >> 4, e0 = (idx & 15) * 4;
        ushort4 u;
        if (m < NK_) u = *(const ushort4*)&kbuf[((size_t)bh * NK_ + m) * 64 + e0];
        else { u.x = 0; u.y = 0; u.z = 0; u.w = 0; }
        *(ushort4*)(ktB + KTB(m, e0)) = u;
    }
    __syncthreads();

    // ---- P2: q-proj: Q[64j][64e] = XT[j][c] * QW[e][c]^T ----
    {
        bf16x8 aq[4];
#pragma unroll
        for (int ks = 0; ks < 4; ++ks)
            aq[ks] = *(const bf16x8*)(xtB + XTB(jw + lo, ks * 32 + hi * 8));
#pragma unroll
        for (int et = 0; et < 4; ++et) {
            f32x4 acc = {0.f, 0.f, 0.f, 0.f};
#pragma unroll
            for (int ks = 0; ks < 4; ++ks) {
                bf16x8 bq = *(const bf16x8*)(qwB + QWB(et * 16 + lo, ks * 32 + hi * 8));
                acc = __builtin_amdgcn_mfma_f32_16x16x32_bf16(aq[ks], bq, acc, 0, 0, 0);
            }
            float qb = q_b[h * 64 + et * 16 + lo];
#pragma unroll
            for (int r = 0; r < 4; ++r)
                *(unsigned short*)(qsB + QSB(jw + hi * 4 + r, et * 16 + lo)) = f2b(acc[r] + qb);
        }
    }
    __syncthreads();

    // ---- P3: S = Q * K^T (k pre-scaled), softmax, normalized P -> PS ----
    {
        bf16x8 as2[2];
#pragma unroll
        for (int ks = 0; ks < 2; ++ks)
            as2[ks] = *(const bf16x8*)(qsB + QSB(jw + lo, ks * 32 + hi * 8));
        f32x4 s[15];
#pragma unroll
        for (int mt = 0; mt < 15; ++mt) {
            f32x4 acc = {0.f, 0.f, 0.f, 0.f};
#pragma unroll
            for (int ks = 0; ks < 2; ++ks) {
                bf16x8 bk = *(const bf16x8*)(ktB + KTB(mt * 16 + lo, ks * 32 + hi * 8));
                acc = __builtin_amdgcn_mfma_f32_16x16x32_bf16(as2[ks], bk, acc, 0, 0, 0);
            }
            s[mt] = acc;
        }
        // mask invalid cols (m = 224 + lo, lo>=1)
        if (lo != 0) {
#pragma unroll
            for (int r = 0; r < 4; ++r) s[14][r] = -1e30f;
        }
        // row max
        float mx[4];
#pragma unroll
        for (int r = 0; r < 4; ++r) {
            float m0 = s[0][r];
#pragma unroll
            for (int mt = 1; mt < 15; ++mt) m0 = fmaxf(m0, s[mt][r]);
            mx[r] = m0;
        }
#pragma unroll
        for (int d = 1; d < 16; d <<= 1) {
#pragma unroll
            for (int r = 0; r < 4; ++r) mx[r] = fmaxf(mx[r], __shfl_xor(mx[r], d));
        }
        // exp + row sum
        float sm[4] = {0.f, 0.f, 0.f, 0.f};
#pragma unroll
        for (int mt = 0; mt < 15; ++mt) {
#pragma unroll
            for (int r = 0; r < 4; ++r) {
                float pe = __expf(s[mt][r] - mx[r]);
                s[mt][r] = pe;
                sm[r] += pe;
            }
        }
#pragma unroll
        for (int d = 1; d < 16; d <<= 1) {
#pragma unroll
            for (int r = 0; r < 4; ++r) sm[r] += __shfl_xor(sm[r], d);
        }
        float rinv[4];
#pragma unroll
        for (int r = 0; r < 4; ++r) rinv[r] = 1.f / sm[r];
        // write normalized P (bf16) + zero tail cols 240..255
#pragma unroll
        for (int mt = 0; mt < 15; ++mt) {
#pragma unroll
            for (int r = 0; r < 4; ++r)
                *(unsigned short*)(psB + PSB(jw + hi * 4 + r, mt * 16 + lo)) =
                    f2b(s[mt][r] * rinv[r]);
        }
#pragma unroll
        for (int r = 0; r < 4; ++r)
            *(unsigned short*)(psB + PSB(jw + hi * 4 + r, 240 + lo)) = 0;
    }
    __syncthreads();

    // ---- P4: O = P * V  (B-fragments straight from global vbuf, L2-resident) ----
    {
        bf16x8 ap[8];
#pragma unroll
        for (int ks = 0; ks < 8; ++ks)
            ap[ks] = *(const bf16x8*)(psB + PSB(jw + lo, ks * 32 + hi * 8));
#pragma unroll
        for (int et = 0; et < 4; ++et) {
            int e = et * 16 + lo;
            const unsigned short* vp = vbuf + ((size_t)bh * 64 + e) * 256;
            f32x4 acc = {0.f, 0.f, 0.f, 0.f};
#pragma unroll
            for (int ks = 0; ks < 8; ++ks) {
                bf16x8 bv = *(const bf16x8*)(vp + ks * 32 + hi * 8);
                acc = __builtin_amdgcn_mfma_f32_16x16x32_bf16(ap[ks], bv, acc, 0, 0, 0);
            }
#pragma unroll
            for (int r = 0; r < 4; ++r)
                RB.olds[(jw + hi * 4 + r) * 65 + e] = acc[r];
        }
    }
    __syncthreads();

    // ---- P5: coalesced store via transpose buffer ----
#pragma unroll
    for (int it = 0; it < 16; ++it) {
        int idx = it * 256 + tid;
        int e = idx >> 6, j = idx & 63;
        out[((size_t)bb * 128 + h * 64 + e) * N_ + n0 + j] = RB.olds[j * 65 + e];
    }
}

extern "C" void kernel_launch(void* const* d_in, const int* in_sizes, int n_in,
                              void* d_out, int out_size, void* d_ws, size_t ws_size,
                              hipStream_t stream) {
    const float* x       = (const float*)d_in[0];
    const float* q_w     = (const float*)d_in[1];
    const float* q_b     = (const float*)d_in[2];
    const float* kv_w    = (const float*)d_in[3];
    const float* kv_b    = (const float*)d_in[4];
    const float* sr1_w   = (const float*)d_in[5];
    const float* sr1_g   = (const float*)d_in[6];
    const float* sr1_b   = (const float*)d_in[7];
    const float* sr1_m   = (const float*)d_in[8];
    const float* sr1_v   = (const float*)d_in[9];
    const float* sr2_w   = (const float*)d_in[10];
    const float* sr2_g   = (const float*)d_in[11];
    const float* sr2_b   = (const float*)d_in[12];
    const float* sr2_m   = (const float*)d_in[13];
    const float* sr2_v   = (const float*)d_in[14];
    const float* local_w = (const float*)d_in[15];
    const float* local_b = (const float*)d_in[16];

    float* kv1 = (float*)d_ws;                                   // 32*128*225 f32
    float* kv2 = kv1 + (size_t)B_ * C_ * NK_;                    // 32*128*225 f32
    unsigned short* kbuf = (unsigned short*)(kv2 + (size_t)B_ * C_ * NK_); // 32*2*225*64
    unsigned short* vbuf = kbuf + (size_t)B_ * 2 * NK_ * 64;     // 32*2*64*256

    sr_kernel<<<B_ * C_, 256, 0, stream>>>(x, sr1_w, sr1_g, sr1_b, sr1_m, sr1_v,
                                           sr2_w, sr2_g, sr2_b, sr2_m, sr2_v, kv1);
    local_kernel<<<B_ * C_, 256, 0, stream>>>(kv1, local_w, local_b, kv2);
    kvproj_kernel<<<dim3(B_, 8), 256, 0, stream>>>(kv2, kv_w, kv_b, kbuf, vbuf);
    attn_kernel<<<dim3(49, 2, B_), 256, 0, stream>>>(x, q_w, q_b, kbuf, vbuf,
                                                     (float*)d_out);
}